// Round 5
// baseline (1774.849 us; speedup 1.0000x reference)
//
#include <hip/hip_runtime.h>
#include <hip/hip_bf16.h>
#include <math.h>

#define HIDDEN 128
#define EPS_G 1e-8f
#define NBMAX 1024          // max src-buckets supported by the 1-block scan

// ---------------------------------------------------------------------------
// Kernel 0: PetB[t][c] = b1[c] + sum_{k<16} etype_emb[t][k] * W1[256+k][c]
// ---------------------------------------------------------------------------
__global__ __launch_bounds__(256) void etype_proj_kernel(
    const float* __restrict__ ee, const float* __restrict__ W1,
    const float* __restrict__ b1, float* __restrict__ PetB, int n_etypes)
{
    int gid = blockIdx.x * 256 + threadIdx.x;
    int t = gid >> 7;
    int c = gid & 127;
    if (t >= n_etypes) return;
    float acc = b1[c];
    #pragma unroll
    for (int k = 0; k < 16; ++k)
        acc = fmaf(ee[t * 16 + k], W1[(256 + k) * 128 + c], acc);
    PetB[t * 128 + c] = acc;
}

// ---------------------------------------------------------------------------
// Kernel 1: P[m][0:256] = x[m] @ [W1a | W1b].
// A-operand comes from REGISTERS via wave-broadcast global loads (each x
// element loaded exactly once chip-wide); only B (W1 tile) is staged in LDS.
// LDS per inner kk: 32B/thread (0.5 B/FMA) -> VALU-bound.
// k-accumulation order identical to the known-pass round-1 kernel.
// ---------------------------------------------------------------------------
__global__ __launch_bounds__(256) void node_proj_kernel(
    const float* __restrict__ x, const float* __restrict__ W1,
    float* __restrict__ P, int n_nodes)
{
    __shared__ float Bs[32 * 256];   // 32 KB

    const int tid = threadIdx.x;
    const int m0  = blockIdx.x * 64;
    const int tm  = tid >> 5;        // 0..7 -> owns rows m0+tm*8 .. +7
    const int tn  = tid & 31;        // cols tn*4..+3 and 128+tn*4..+3

    float acc[8][8];
    #pragma unroll
    for (int i = 0; i < 8; ++i)
        #pragma unroll
        for (int j = 0; j < 8; ++j) acc[i][j] = 0.f;

    const int r0 = m0 + tm * 8;
    const bool full = (r0 + 8 <= n_nodes);
    const float* xb = x + (size_t)r0 * 128;

    for (int kc = 0; kc < 128; kc += 32) {
        // --- stage B' [32 k][256 c']: 2048 float4 loads ---
        #pragma unroll
        for (int i = 0; i < 8; ++i) {
            int l   = tid + i * 256;
            int row = l >> 6;              // 0..31 (k)
            int c4  = (l & 63) << 2;       // 0..252
            const float* sp = (c4 < 128)
                ? (W1 + (size_t)(kc + row) * 128 + c4)
                : (W1 + (size_t)(128 + kc + row) * 128 + (c4 - 128));
            *(float4*)&Bs[row * 256 + c4] = *(const float4*)sp;
        }
        __syncthreads();

        #pragma unroll
        for (int g = 0; g < 8; ++g) {      // groups of 4 k
            float4 av[8];
            if (full) {
                #pragma unroll
                for (int i = 0; i < 8; ++i)
                    av[i] = *(const float4*)(xb + (size_t)i * 128 + kc + g * 4);
            } else {
                #pragma unroll
                for (int i = 0; i < 8; ++i) {
                    int gr = r0 + i;
                    if (gr >= n_nodes) gr = n_nodes - 1;   // stores guarded
                    av[i] = *(const float4*)(x + (size_t)gr * 128 + kc + g * 4);
                }
            }
            #pragma unroll
            for (int j = 0; j < 4; ++j) {
                int kk = g * 4 + j;
                float4 b0  = *(const float4*)&Bs[kk * 256 + tn * 4];
                float4 b1v = *(const float4*)&Bs[kk * 256 + 128 + tn * 4];
                #pragma unroll
                for (int i = 0; i < 8; ++i) {
                    float a = (j == 0) ? av[i].x : (j == 1) ? av[i].y
                            : (j == 2) ? av[i].z : av[i].w;
                    acc[i][0] = fmaf(a, b0.x,  acc[i][0]);
                    acc[i][1] = fmaf(a, b0.y,  acc[i][1]);
                    acc[i][2] = fmaf(a, b0.z,  acc[i][2]);
                    acc[i][3] = fmaf(a, b0.w,  acc[i][3]);
                    acc[i][4] = fmaf(a, b1v.x, acc[i][4]);
                    acc[i][5] = fmaf(a, b1v.y, acc[i][5]);
                    acc[i][6] = fmaf(a, b1v.z, acc[i][6]);
                    acc[i][7] = fmaf(a, b1v.w, acc[i][7]);
                }
            }
        }
        __syncthreads();
    }

    #pragma unroll
    for (int i = 0; i < 8; ++i) {
        int gr = r0 + i;
        if (gr < n_nodes) {
            float4 w0 = make_float4(acc[i][0], acc[i][1], acc[i][2], acc[i][3]);
            float4 w1 = make_float4(acc[i][4], acc[i][5], acc[i][6], acc[i][7]);
            *(float4*)(P + (size_t)gr * 256 + tn * 4)       = w0;
            *(float4*)(P + (size_t)gr * 256 + 128 + tn * 4) = w1;
        }
    }
}

// ---------------------------------------------------------------------------
// Binning pipeline: bucket edges by (src >> 7) for XCD-local src gathers.
// ---------------------------------------------------------------------------
__global__ __launch_bounds__(1024) void zero_hist_kernel(int* __restrict__ hist)
{
    hist[threadIdx.x] = 0;   // 1 block, 1024 threads, NBMAX ints
}

__global__ __launch_bounds__(256) void hist_kernel(
    const int* __restrict__ ei, int* __restrict__ hist, int E, int NB)
{
    __shared__ int lh[NBMAX];
    for (int i = threadIdx.x; i < NB; i += 256) lh[i] = 0;
    __syncthreads();
    for (int e = blockIdx.x * 256 + threadIdx.x; e < E; e += gridDim.x * 256)
        atomicAdd(&lh[ei[e] >> 7], 1);
    __syncthreads();
    for (int i = threadIdx.x; i < NB; i += 256)
        if (lh[i]) atomicAdd(&hist[i], lh[i]);
}

__global__ __launch_bounds__(1024) void scan_kernel(
    const int* __restrict__ hist, int* __restrict__ cursor, int NB)
{
    __shared__ int buf[2][NBMAX];
    int tid = threadIdx.x;
    int v = (tid < NB) ? hist[tid] : 0;
    buf[0][tid] = v;
    __syncthreads();
    int cur = 0;
    for (int off = 1; off < NBMAX; off <<= 1) {
        int t = buf[cur][tid] + ((tid >= off) ? buf[cur][tid - off] : 0);
        buf[cur ^ 1][tid] = t;
        cur ^= 1;
        __syncthreads();
    }
    if (tid < NB) cursor[tid] = buf[cur][tid] - v;   // exclusive prefix
}

__global__ __launch_bounds__(256) void scatter_kernel(
    const int* __restrict__ ei, int* __restrict__ cursor,
    int* __restrict__ perm, int* __restrict__ iperm, int E)
{
    for (int e = blockIdx.x * 256 + threadIdx.x; e < E; e += gridDim.x * 256) {
        int b = ei[e] >> 7;
        int pos = atomicAdd(&cursor[b], 1);
        perm[pos] = e;
        iperm[e] = pos;
    }
}

// ---------------------------------------------------------------------------
// Kernel 2 (binned): 16 lanes/edge, edges in bucket order via perm.
// Bijective XCD swizzle keeps each bucket's blocks on one XCD.
// Results written bucket-ordered to tmp[s][3]; unpermuted afterwards.
// ---------------------------------------------------------------------------
__global__ __launch_bounds__(256) void edge_binned_kernel(
    const int* __restrict__ perm, const int* __restrict__ ei,
    const int* __restrict__ et, const float* __restrict__ u,
    const float* __restrict__ P, const float* __restrict__ PetB,
    const float* __restrict__ W2, const float* __restrict__ b2,
    float* __restrict__ tmp, int E)
{
    // bijective XCD-aware swizzle (m204): consecutive wgid -> same XCD
    int nwg  = gridDim.x;
    int orig = blockIdx.x;
    int q = nwg >> 3, r = nwg & 7;
    int xcd = orig & 7;
    int o8  = orig >> 3;
    int wgid = ((xcd < r) ? xcd * (q + 1) : r * (q + 1) + (xcd - r) * q) + o8;

    int s = wgid * 16 + (threadIdx.x >> 4);
    int l = threadIdx.x & 15;
    if (s >= E) return;
    int e = perm[s];

    int src = ei[e];
    int dst = ei[E + e];
    int t   = et[e];
    float uu = u[e];

    const float4* ps = (const float4*)(P + (size_t)src * 256);
    const float4* pd = (const float4*)(P + (size_t)dst * 256 + 128);
    const float4* pe = (const float4*)(PetB + (size_t)t * 128);
    const float4* w2 = (const float4*)W2;

    float partial = 0.f;
    #pragma unroll
    for (int j = 0; j < 2; ++j) {
        int idx = l * 2 + j;
        float4 a = ps[idx];
        float4 b = pd[idx];
        float4 c = pe[idx];
        float4 w = w2[idx];
        float h0 = fmaxf(a.x + b.x + c.x, 0.f);
        float h1 = fmaxf(a.y + b.y + c.y, 0.f);
        float h2 = fmaxf(a.z + b.z + c.z, 0.f);
        float h3 = fmaxf(a.w + b.w + c.w, 0.f);
        partial = fmaf(h0, w.x, partial);
        partial = fmaf(h1, w.y, partial);
        partial = fmaf(h2, w.z, partial);
        partial = fmaf(h3, w.w, partial);
    }
    partial += __shfl_xor(partial, 1);
    partial += __shfl_xor(partial, 2);
    partial += __shfl_xor(partial, 4);
    partial += __shfl_xor(partial, 8);

    if (l == 0) {
        float logit = partial + b2[0];
        float g  = logf(uu + EPS_G) - logf(1.f - uu + EPS_G);
        float z  = logit + g;                       // TEMP = 1.0
        float yv = 1.f / (1.f + expf(-z));
        float yh = yv > 0.5f ? 1.f : 0.f;
        float yst = (yh - yv) + yv;
        tmp[(size_t)s * 3 + 0] = logit;
        tmp[(size_t)s * 3 + 1] = yv;
        tmp[(size_t)s * 3 + 2] = yst;
    }
}

__global__ __launch_bounds__(256) void unpermute_kernel(
    const int* __restrict__ iperm, const float* __restrict__ tmp,
    float* __restrict__ out, int E)
{
    int e = blockIdx.x * 256 + threadIdx.x;
    if (e >= E) return;
    int s = iperm[e];
    out[e]         = tmp[(size_t)s * 3 + 0];
    out[E + e]     = tmp[(size_t)s * 3 + 1];
    out[2 * E + e] = tmp[(size_t)s * 3 + 2];
}

// ---------------------------------------------------------------------------
// Kernel 2 (mid-tier fallback, unbinned; round-4 known-pass version).
// ---------------------------------------------------------------------------
__global__ __launch_bounds__(256) void edge_kernel(
    const int* __restrict__ ei, const int* __restrict__ et,
    const float* __restrict__ u, const float* __restrict__ P,
    const float* __restrict__ PetB, const float* __restrict__ W2,
    const float* __restrict__ b2, float* __restrict__ out, int E)
{
    int gtid = blockIdx.x * 256 + threadIdx.x;
    int e = gtid >> 4;
    int l = gtid & 15;
    if (e >= E) return;

    int src = ei[e];
    int dst = ei[E + e];
    int t   = et[e];
    float uu = u[e];

    const float4* ps = (const float4*)(P + (size_t)src * 256);
    const float4* pd = (const float4*)(P + (size_t)dst * 256 + 128);
    const float4* pe = (const float4*)(PetB + (size_t)t * 128);
    const float4* w2 = (const float4*)W2;

    float partial = 0.f;
    #pragma unroll
    for (int j = 0; j < 2; ++j) {
        int idx = l * 2 + j;
        float4 a = ps[idx];
        float4 b = pd[idx];
        float4 c = pe[idx];
        float4 w = w2[idx];
        float h0 = fmaxf(a.x + b.x + c.x, 0.f);
        float h1 = fmaxf(a.y + b.y + c.y, 0.f);
        float h2 = fmaxf(a.z + b.z + c.z, 0.f);
        float h3 = fmaxf(a.w + b.w + c.w, 0.f);
        partial = fmaf(h0, w.x, partial);
        partial = fmaf(h1, w.y, partial);
        partial = fmaf(h2, w.z, partial);
        partial = fmaf(h3, w.w, partial);
    }
    partial += __shfl_xor(partial, 1);
    partial += __shfl_xor(partial, 2);
    partial += __shfl_xor(partial, 4);
    partial += __shfl_xor(partial, 8);

    if (l == 0) {
        float logit = partial + b2[0];
        float g  = logf(uu + EPS_G) - logf(1.f - uu + EPS_G);
        float z  = logit + g;
        float yv = 1.f / (1.f + expf(-z));
        float yh = yv > 0.5f ? 1.f : 0.f;
        float yst = (yh - yv) + yv;
        out[e]         = logit;
        out[E + e]     = yv;
        out[2 * E + e] = yst;
    }
}

// ---------------------------------------------------------------------------
// Lowest-tier fallback: wave(64)/edge direct MLP.
// ---------------------------------------------------------------------------
__global__ __launch_bounds__(256) void edge_direct_kernel(
    const float* __restrict__ x, const int* __restrict__ ei,
    const int* __restrict__ et, const float* __restrict__ u,
    const float* __restrict__ ee, const float* __restrict__ W1,
    const float* __restrict__ b1, const float* __restrict__ W2,
    const float* __restrict__ b2, float* __restrict__ out, int E)
{
    int wid  = (blockIdx.x * 256 + threadIdx.x) >> 6;
    int lane = threadIdx.x & 63;
    if (wid >= E) return;
    int src = ei[wid], dst = ei[E + wid], t = et[wid];
    int c0 = lane * 2;
    float acc0 = b1[c0], acc1 = b1[c0 + 1];
    for (int k = 0; k < 128; ++k) {
        float xs = x[(size_t)src * 128 + k];
        acc0 = fmaf(xs, W1[k * 128 + c0], acc0);
        acc1 = fmaf(xs, W1[k * 128 + c0 + 1], acc1);
    }
    for (int k = 0; k < 128; ++k) {
        float xd = x[(size_t)dst * 128 + k];
        acc0 = fmaf(xd, W1[(128 + k) * 128 + c0], acc0);
        acc1 = fmaf(xd, W1[(128 + k) * 128 + c0 + 1], acc1);
    }
    for (int k = 0; k < 16; ++k) {
        float ev = ee[t * 16 + k];
        acc0 = fmaf(ev, W1[(256 + k) * 128 + c0], acc0);
        acc1 = fmaf(ev, W1[(256 + k) * 128 + c0 + 1], acc1);
    }
    float partial = fmaxf(acc0, 0.f) * W2[c0] + fmaxf(acc1, 0.f) * W2[c0 + 1];
    #pragma unroll
    for (int off = 1; off < 64; off <<= 1) partial += __shfl_xor(partial, off);
    if (lane == 0) {
        float logit = partial + b2[0];
        float uu = u[wid];
        float g  = logf(uu + EPS_G) - logf(1.f - uu + EPS_G);
        float z  = logit + g;
        float yv = 1.f / (1.f + expf(-z));
        float yh = yv > 0.5f ? 1.f : 0.f;
        float yst = (yh - yv) + yv;
        out[wid]         = logit;
        out[E + wid]     = yv;
        out[2 * E + wid] = yst;
    }
}

// ---------------------------------------------------------------------------
extern "C" void kernel_launch(void* const* d_in, const int* in_sizes, int n_in,
                              void* d_out, int out_size, void* d_ws, size_t ws_size,
                              hipStream_t stream)
{
    const float* x   = (const float*)d_in[0];
    const int*   ei  = (const int*)d_in[1];
    const int*   et  = (const int*)d_in[2];
    const float* u   = (const float*)d_in[3];
    const float* ee  = (const float*)d_in[4];
    const float* W1  = (const float*)d_in[5];
    const float* b1  = (const float*)d_in[6];
    const float* W2  = (const float*)d_in[7];
    const float* b2  = (const float*)d_in[8];
    float* out = (float*)d_out;

    const int n_nodes  = in_sizes[0] / HIDDEN;   // 100000
    const int E        = in_sizes[2];             // 1600000
    const int n_etypes = in_sizes[4] / 16;        // 512
    const int NB       = (n_nodes + 127) >> 7;    // 782 src-buckets

    auto align256 = [](size_t v) { return (v + 255) & ~(size_t)255; };
    const size_t needP   = (size_t)n_nodes * 256 * sizeof(float);    // 102.4 MB
    const size_t needPet = (size_t)n_etypes * 128 * sizeof(float);   // 256 KB
    const size_t off_perm  = align256(needP + needPet);
    const size_t off_iperm = align256(off_perm  + (size_t)E * 4);
    const size_t off_tmp   = align256(off_iperm + (size_t)E * 4);
    const size_t off_hist  = align256(off_tmp   + (size_t)E * 12);
    const size_t off_cur   = off_hist + NBMAX * 4;
    const size_t need_full = off_cur + NBMAX * 4;

    const bool mid  = (ws_size >= needP + needPet);
    const bool binz = (ws_size >= need_full) && (NB <= NBMAX);

    if (mid) {
        float* P    = (float*)d_ws;
        float* PetB = (float*)((char*)d_ws + needP);

        hipLaunchKernelGGL(etype_proj_kernel,
                           dim3((n_etypes * 128 + 255) / 256), dim3(256), 0, stream,
                           ee, W1, b1, PetB, n_etypes);
        hipLaunchKernelGGL(node_proj_kernel,
                           dim3((n_nodes + 63) / 64), dim3(256), 0, stream,
                           x, W1, P, n_nodes);

        if (binz) {
            int*   perm   = (int*)((char*)d_ws + off_perm);
            int*   iperm  = (int*)((char*)d_ws + off_iperm);
            float* tmp    = (float*)((char*)d_ws + off_tmp);
            int*   hist   = (int*)((char*)d_ws + off_hist);
            int*   cursor = (int*)((char*)d_ws + off_cur);

            hipLaunchKernelGGL(zero_hist_kernel, dim3(1), dim3(NBMAX), 0, stream,
                               hist);
            hipLaunchKernelGGL(hist_kernel, dim3(512), dim3(256), 0, stream,
                               ei, hist, E, NB);
            hipLaunchKernelGGL(scan_kernel, dim3(1), dim3(NBMAX), 0, stream,
                               hist, cursor, NB);
            hipLaunchKernelGGL(scatter_kernel, dim3(512), dim3(256), 0, stream,
                               ei, cursor, perm, iperm, E);

            int nwg = (E + 15) / 16;   // 16 edges per 256-thread block
            hipLaunchKernelGGL(edge_binned_kernel, dim3(nwg), dim3(256), 0, stream,
                               perm, ei, et, u, P, PetB, W2, b2, tmp, E);
            hipLaunchKernelGGL(unpermute_kernel, dim3((E + 255) / 256), dim3(256),
                               0, stream, iperm, tmp, out, E);
        } else {
            hipLaunchKernelGGL(edge_kernel,
                               dim3((int)(((size_t)E * 16 + 255) / 256)), dim3(256),
                               0, stream, ei, et, u, P, PetB, W2, b2, out, E);
        }
    } else {
        hipLaunchKernelGGL(edge_direct_kernel,
                           dim3((E + 3) / 4), dim3(256), 0, stream,
                           x, ei, et, u, ee, W1, b1, W2, b2, out, E);
    }
}

// Round 7
// 510.902 us; speedup vs baseline: 3.4740x; 3.4740x over previous
//
#include <hip/hip_runtime.h>
#include <hip/hip_bf16.h>
#include <math.h>

#define HIDDEN 128
#define EPS_G 1e-8f

// ---------------------------------------------------------------------------
// Kernel 0: PetB[t][c] = b1[c] + sum_{k<16} etype_emb[t][k] * W1[256+k][c]
// ---------------------------------------------------------------------------
__global__ __launch_bounds__(256) void etype_proj_kernel(
    const float* __restrict__ ee, const float* __restrict__ W1,
    const float* __restrict__ b1, float* __restrict__ PetB, int n_etypes)
{
    int gid = blockIdx.x * 256 + threadIdx.x;
    int t = gid >> 7;
    int c = gid & 127;
    if (t >= n_etypes) return;
    float acc = b1[c];
    #pragma unroll
    for (int k = 0; k < 16; ++k)
        acc = fmaf(ee[t * 16 + k], W1[(256 + k) * 128 + c], acc);
    PetB[t * 128 + c] = acc;
}

// ---------------------------------------------------------------------------
// Kernel 1: P[m][0:256] = x[m] @ [W1a | W1b].
// A-operand from registers via wave-broadcast global loads, loaded per-row
// and consumed IMMEDIATELY (no av[] array -> nothing runtime-indexable ->
// no scratch; round-5 spilled via rule #20). B staged in LDS, pre-read into
// bv registers once per 4-k group: LDS = 0.5 B/FMA -> VALU-bound.
// k-accumulation order identical to the known-pass round-1/4 kernels.
// ---------------------------------------------------------------------------
__global__ __launch_bounds__(256, 3) void node_proj_kernel(
    const float* __restrict__ x, const float* __restrict__ W1,
    float* __restrict__ P, int n_nodes)
{
    __shared__ float Bs[32 * 256];   // 32 KB

    const int tid = threadIdx.x;
    const int m0  = blockIdx.x * 64;
    const int tm  = tid >> 5;        // 0..7 -> owns rows m0+tm*8 .. +7
    const int tn  = tid & 31;        // cols tn*4..+3 and 128+tn*4..+3

    float acc[8][8];
    #pragma unroll
    for (int i = 0; i < 8; ++i)
        #pragma unroll
        for (int j = 0; j < 8; ++j) acc[i][j] = 0.f;

    const int r0  = m0 + tm * 8;
    const int nm1 = n_nodes - 1;

    for (int kc = 0; kc < 128; kc += 32) {
        // --- stage B' [32 k][256 c']: 2048 float4 loads, 8/thread ---
        #pragma unroll
        for (int i = 0; i < 8; ++i) {
            int l   = tid + i * 256;
            int row = l >> 6;              // 0..31 (k)
            int c4  = (l & 63) << 2;       // 0..252
            const float* sp = (c4 < 128)
                ? (W1 + (size_t)(kc + row) * 128 + c4)
                : (W1 + (size_t)(128 + kc + row) * 128 + (c4 - 128));
            *(float4*)&Bs[row * 256 + c4] = *(const float4*)sp;
        }
        __syncthreads();

        #pragma unroll
        for (int g = 0; g < 8; ++g) {          // 4 k per group
            // B for these 4 k -> registers (8x ds_read_b128 per 256 FMA)
            float4 bv0[4], bv1[4];
            #pragma unroll
            for (int j = 0; j < 4; ++j) {
                bv0[j] = *(const float4*)&Bs[(g * 4 + j) * 256 + tn * 4];
                bv1[j] = *(const float4*)&Bs[(g * 4 + j) * 256 + 128 + tn * 4];
            }
            #pragma unroll
            for (int i = 0; i < 8; ++i) {
                int gr = r0 + i;
                if (gr > nm1) gr = nm1;        // clamp; stores guarded
                float4 av = *(const float4*)(x + (size_t)gr * 128 + kc + g * 4);
                #pragma unroll
                for (int j = 0; j < 4; ++j) {
                    float a = (j == 0) ? av.x : (j == 1) ? av.y
                            : (j == 2) ? av.z : av.w;
                    acc[i][0] = fmaf(a, bv0[j].x, acc[i][0]);
                    acc[i][1] = fmaf(a, bv0[j].y, acc[i][1]);
                    acc[i][2] = fmaf(a, bv0[j].z, acc[i][2]);
                    acc[i][3] = fmaf(a, bv0[j].w, acc[i][3]);
                    acc[i][4] = fmaf(a, bv1[j].x, acc[i][4]);
                    acc[i][5] = fmaf(a, bv1[j].y, acc[i][5]);
                    acc[i][6] = fmaf(a, bv1[j].z, acc[i][6]);
                    acc[i][7] = fmaf(a, bv1[j].w, acc[i][7]);
                }
            }
        }
        __syncthreads();
    }

    #pragma unroll
    for (int i = 0; i < 8; ++i) {
        int gr = r0 + i;
        if (gr < n_nodes) {
            float4 w0 = make_float4(acc[i][0], acc[i][1], acc[i][2], acc[i][3]);
            float4 w1 = make_float4(acc[i][4], acc[i][5], acc[i][6], acc[i][7]);
            *(float4*)(P + (size_t)gr * 256 + tn * 4)       = w0;
            *(float4*)(P + (size_t)gr * 256 + 128 + tn * 4) = w1;
        }
    }
}

// ---------------------------------------------------------------------------
// Kernel 2: per edge, 16 lanes/edge, all fp32 (known-pass, 221 us).
// ---------------------------------------------------------------------------
__global__ __launch_bounds__(256) void edge_kernel(
    const int* __restrict__ ei, const int* __restrict__ et,
    const float* __restrict__ u, const float* __restrict__ P,
    const float* __restrict__ PetB, const float* __restrict__ W2,
    const float* __restrict__ b2, float* __restrict__ out, int E)
{
    int gtid = blockIdx.x * 256 + threadIdx.x;
    int e = gtid >> 4;
    int l = gtid & 15;
    if (e >= E) return;

    int src = ei[e];
    int dst = ei[E + e];
    int t   = et[e];
    float uu = u[e];

    const float4* ps = (const float4*)(P + (size_t)src * 256);
    const float4* pd = (const float4*)(P + (size_t)dst * 256 + 128);
    const float4* pe = (const float4*)(PetB + (size_t)t * 128);
    const float4* w2 = (const float4*)W2;

    float partial = 0.f;
    #pragma unroll
    for (int j = 0; j < 2; ++j) {
        int idx = l * 2 + j;
        float4 a = ps[idx];
        float4 b = pd[idx];
        float4 c = pe[idx];
        float4 w = w2[idx];
        float h0 = fmaxf(a.x + b.x + c.x, 0.f);
        float h1 = fmaxf(a.y + b.y + c.y, 0.f);
        float h2 = fmaxf(a.z + b.z + c.z, 0.f);
        float h3 = fmaxf(a.w + b.w + c.w, 0.f);
        partial = fmaf(h0, w.x, partial);
        partial = fmaf(h1, w.y, partial);
        partial = fmaf(h2, w.z, partial);
        partial = fmaf(h3, w.w, partial);
    }
    partial += __shfl_xor(partial, 1);
    partial += __shfl_xor(partial, 2);
    partial += __shfl_xor(partial, 4);
    partial += __shfl_xor(partial, 8);

    if (l == 0) {
        float logit = partial + b2[0];
        float g  = logf(uu + EPS_G) - logf(1.f - uu + EPS_G);
        float z  = logit + g;                       // TEMP = 1.0
        float yv = 1.f / (1.f + expf(-z));
        float yh = yv > 0.5f ? 1.f : 0.f;
        float yst = (yh - yv) + yv;
        out[e]         = logit;
        out[E + e]     = yv;
        out[2 * E + e] = yst;
    }
}

// ---------------------------------------------------------------------------
// Fallback (ws too small): wave(64)/edge direct MLP, fp32.
// ---------------------------------------------------------------------------
__global__ __launch_bounds__(256) void edge_direct_kernel(
    const float* __restrict__ x, const int* __restrict__ ei,
    const int* __restrict__ et, const float* __restrict__ u,
    const float* __restrict__ ee, const float* __restrict__ W1,
    const float* __restrict__ b1, const float* __restrict__ W2,
    const float* __restrict__ b2, float* __restrict__ out, int E)
{
    int wid  = (blockIdx.x * 256 + threadIdx.x) >> 6;
    int lane = threadIdx.x & 63;
    if (wid >= E) return;
    int src = ei[wid], dst = ei[E + wid], t = et[wid];
    int c0 = lane * 2;
    float acc0 = b1[c0], acc1 = b1[c0 + 1];
    for (int k = 0; k < 128; ++k) {
        float xs = x[(size_t)src * 128 + k];
        acc0 = fmaf(xs, W1[k * 128 + c0], acc0);
        acc1 = fmaf(xs, W1[k * 128 + c0 + 1], acc1);
    }
    for (int k = 0; k < 128; ++k) {
        float xd = x[(size_t)dst * 128 + k];
        acc0 = fmaf(xd, W1[(128 + k) * 128 + c0], acc0);
        acc1 = fmaf(xd, W1[(128 + k) * 128 + c0 + 1], acc1);
    }
    for (int k = 0; k < 16; ++k) {
        float ev = ee[t * 16 + k];
        acc0 = fmaf(ev, W1[(256 + k) * 128 + c0], acc0);
        acc1 = fmaf(ev, W1[(256 + k) * 128 + c0 + 1], acc1);
    }
    float partial = fmaxf(acc0, 0.f) * W2[c0] + fmaxf(acc1, 0.f) * W2[c0 + 1];
    #pragma unroll
    for (int off = 1; off < 64; off <<= 1) partial += __shfl_xor(partial, off);
    if (lane == 0) {
        float logit = partial + b2[0];
        float uu = u[wid];
        float g  = logf(uu + EPS_G) - logf(1.f - uu + EPS_G);
        float z  = logit + g;
        float yv = 1.f / (1.f + expf(-z));
        float yh = yv > 0.5f ? 1.f : 0.f;
        float yst = (yh - yv) + yv;
        out[wid]         = logit;
        out[E + wid]     = yv;
        out[2 * E + wid] = yst;
    }
}

// ---------------------------------------------------------------------------
extern "C" void kernel_launch(void* const* d_in, const int* in_sizes, int n_in,
                              void* d_out, int out_size, void* d_ws, size_t ws_size,
                              hipStream_t stream)
{
    const float* x   = (const float*)d_in[0];
    const int*   ei  = (const int*)d_in[1];
    const int*   et  = (const int*)d_in[2];
    const float* u   = (const float*)d_in[3];
    const float* ee  = (const float*)d_in[4];
    const float* W1  = (const float*)d_in[5];
    const float* b1  = (const float*)d_in[6];
    const float* W2  = (const float*)d_in[7];
    const float* b2  = (const float*)d_in[8];
    float* out = (float*)d_out;

    const int n_nodes  = in_sizes[0] / HIDDEN;   // 100000
    const int E        = in_sizes[2];             // 1600000
    const int n_etypes = in_sizes[4] / 16;        // 512

    const size_t needP   = (size_t)n_nodes * 256 * sizeof(float);    // 102.4 MB
    const size_t needPet = (size_t)n_etypes * 128 * sizeof(float);   // 256 KB

    if (ws_size >= needP + needPet) {
        float* P    = (float*)d_ws;
        float* PetB = (float*)((char*)d_ws + needP);

        hipLaunchKernelGGL(etype_proj_kernel,
                           dim3((n_etypes * 128 + 255) / 256), dim3(256), 0, stream,
                           ee, W1, b1, PetB, n_etypes);
        hipLaunchKernelGGL(node_proj_kernel,
                           dim3((n_nodes + 63) / 64), dim3(256), 0, stream,
                           x, W1, P, n_nodes);
        hipLaunchKernelGGL(edge_kernel,
                           dim3((int)(((size_t)E * 16 + 255) / 256)), dim3(256), 0, stream,
                           ei, et, u, P, PetB, W2, b2, out, E);
    } else {
        hipLaunchKernelGGL(edge_direct_kernel,
                           dim3((E + 3) / 4), dim3(256), 0, stream,
                           x, ei, et, u, ee, W1, b1, W2, b2, out, E);
    }
}

// Round 8
// 491.848 us; speedup vs baseline: 3.6085x; 1.0387x over previous
//
#include <hip/hip_runtime.h>
#include <hip/hip_bf16.h>
#include <math.h>

#define HIDDEN 128
#define EPS_G 1e-8f

__device__ __forceinline__ float rdlane(float v, int lane) {
    return __int_as_float(__builtin_amdgcn_readlane(__float_as_int(v), lane));
}

// ---------------------------------------------------------------------------
// Kernel 0: PetB[t][c] = b1[c] + sum_{k<16} etype_emb[t][k] * W1[256+k][c]
// ---------------------------------------------------------------------------
__global__ __launch_bounds__(256) void etype_proj_kernel(
    const float* __restrict__ ee, const float* __restrict__ W1,
    const float* __restrict__ b1, float* __restrict__ PetB, int n_etypes)
{
    int gid = blockIdx.x * 256 + threadIdx.x;
    int t = gid >> 7;
    int c = gid & 127;
    if (t >= n_etypes) return;
    float acc = b1[c];
    #pragma unroll
    for (int k = 0; k < 16; ++k)
        acc = fmaf(ee[t * 16 + k], W1[(256 + k) * 128 + c], acc);
    PetB[t * 128 + c] = acc;
}

// ---------------------------------------------------------------------------
// Kernel 1 (primary): whole-W1-in-LDS, one barrier, readlane A-broadcast.
// Block = 1024 threads (16 waves), dynamic LDS = 128*256*4 = 131072 B.
// Stage all W1[0:256][:] (reordered as [k][256]) ONCE; sync; then each wave
// owns 8 rows: x row-slices in registers (2 floats/lane), a-values broadcast
// with v_readlane (VALU, not LDS pipe), B via one ds_read_b128 per k.
// Per k per wave: 8 readlane + 32 FMA + 1 b128 -> VALU-bound.
// k ascending, single fma chain per output -> bit-identical to round-1/4.
// ---------------------------------------------------------------------------
__global__ __launch_bounds__(1024, 1) void node_proj_big_kernel(
    const float* __restrict__ x, const float* __restrict__ W1,
    float* __restrict__ P, int n_nodes)
{
    extern __shared__ float Bs[];   // [128 k][256 c] = 131072 B

    const int tid  = threadIdx.x;
    const int lane = tid & 63;
    const int wv   = tid >> 6;                  // 0..15
    const int m0   = blockIdx.x * 128;
    const int r0   = m0 + wv * 8;               // this wave's 8 rows
    const int nm1  = n_nodes - 1;
    const int c0   = lane * 4;                  // this lane's 4 output cols

    // --- stage W1 rows 0..255 -> Bs[k][c'] with c'=col of [W1a|W1b]:
    //     Bs[k][c] = W1[k][c] for c<128, W1[128+k][c-128] for c>=128.
    #pragma unroll
    for (int i = 0; i < 32; ++i) {
        int l   = tid + i * 1024;       // 0..32767 float4 index
        int k   = l >> 6;               // 0..127
        int c4  = (l & 63) << 2;        // 0..252
        const float* sp = (c4 < 128)
            ? (W1 + (size_t)k * 128 + c4)
            : (W1 + (size_t)(128 + k) * 128 + (c4 - 128));
        *(float4*)&Bs[(size_t)k * 256 + c4] = *(const float4*)sp;
    }

    // --- x row-slices into registers: xr[r][j] = x[row_r][2*lane + j]
    float xr[8][2];
    #pragma unroll
    for (int r = 0; r < 8; ++r) {
        int gr = r0 + r;
        if (gr > nm1) gr = nm1;         // clamp; stores guarded
        float2 v = *(const float2*)(x + (size_t)gr * 128 + lane * 2);
        xr[r][0] = v.x;
        xr[r][1] = v.y;
    }

    float acc[8][4];
    #pragma unroll
    for (int r = 0; r < 8; ++r)
        #pragma unroll
        for (int c = 0; c < 4; ++c) acc[r][c] = 0.f;

    __syncthreads();    // the only barrier

    for (int k2 = 0; k2 < 64; ++k2) {   // k = 2*k2 + j
        #pragma unroll
        for (int j = 0; j < 2; ++j) {
            const int k = (k2 << 1) | j;
            float4 bv = *(const float4*)&Bs[(size_t)k * 256 + c0];
            #pragma unroll
            for (int r = 0; r < 8; ++r) {
                float a = rdlane(xr[r][j], k2);   // = x[row_r][k]
                acc[r][0] = fmaf(a, bv.x, acc[r][0]);
                acc[r][1] = fmaf(a, bv.y, acc[r][1]);
                acc[r][2] = fmaf(a, bv.z, acc[r][2]);
                acc[r][3] = fmaf(a, bv.w, acc[r][3]);
            }
        }
    }

    #pragma unroll
    for (int r = 0; r < 8; ++r) {
        int gr = r0 + r;
        if (gr < n_nodes) {
            float4 w = make_float4(acc[r][0], acc[r][1], acc[r][2], acc[r][3]);
            *(float4*)(P + (size_t)gr * 256 + c0) = w;
        }
    }
}

// ---------------------------------------------------------------------------
// Kernel 1 (fallback, known-good r4 version ~193 us): used only if the
// dynamic-LDS attribute cannot be set.
// ---------------------------------------------------------------------------
#define BM 64
#define BK 32
#define BNN 256
#define ASTR 68

__global__ __launch_bounds__(256) void node_proj_kernel(
    const float* __restrict__ x, const float* __restrict__ W1,
    float* __restrict__ P, int n_nodes)
{
    __shared__ float As[BK * ASTR];
    __shared__ float Bs2[BK * BNN];

    const int tid = threadIdx.x;
    const int m0  = blockIdx.x * BM;
    const int tm  = tid >> 5;
    const int tn  = tid & 31;

    float acc[8][8];
    #pragma unroll
    for (int i = 0; i < 8; ++i)
        #pragma unroll
        for (int j = 0; j < 8; ++j) acc[i][j] = 0.f;

    for (int kc = 0; kc < 128; kc += BK) {
        #pragma unroll
        for (int i = 0; i < 2; ++i) {
            int l   = tid + i * 256;
            int row = l >> 3;
            int k4  = (l & 7) << 2;
            int gr  = m0 + row;
            if (gr >= n_nodes) gr = n_nodes - 1;
            float4 v = *(const float4*)(x + (size_t)gr * 128 + kc + k4);
            As[(k4 + 0) * ASTR + row] = v.x;
            As[(k4 + 1) * ASTR + row] = v.y;
            As[(k4 + 2) * ASTR + row] = v.z;
            As[(k4 + 3) * ASTR + row] = v.w;
        }
        #pragma unroll
        for (int i = 0; i < 8; ++i) {
            int l   = tid + i * 256;
            int row = l >> 6;
            int c4  = (l & 63) << 2;
            const float* sp = (c4 < 128)
                ? (W1 + (size_t)(kc + row) * 128 + c4)
                : (W1 + (size_t)(128 + kc + row) * 128 + (c4 - 128));
            *(float4*)&Bs2[row * BNN + c4] = *(const float4*)sp;
        }
        __syncthreads();

        #pragma unroll 4
        for (int kk = 0; kk < BK; ++kk) {
            float4 a0  = *(const float4*)&As[kk * ASTR + tm * 8];
            float4 a1  = *(const float4*)&As[kk * ASTR + tm * 8 + 4];
            float4 b0  = *(const float4*)&Bs2[kk * BNN + tn * 4];
            float4 b1v = *(const float4*)&Bs2[kk * BNN + 128 + tn * 4];
            float a[8] = {a0.x, a0.y, a0.z, a0.w, a1.x, a1.y, a1.z, a1.w};
            #pragma unroll
            for (int i = 0; i < 8; ++i) {
                acc[i][0] = fmaf(a[i], b0.x,  acc[i][0]);
                acc[i][1] = fmaf(a[i], b0.y,  acc[i][1]);
                acc[i][2] = fmaf(a[i], b0.z,  acc[i][2]);
                acc[i][3] = fmaf(a[i], b0.w,  acc[i][3]);
                acc[i][4] = fmaf(a[i], b1v.x, acc[i][4]);
                acc[i][5] = fmaf(a[i], b1v.y, acc[i][5]);
                acc[i][6] = fmaf(a[i], b1v.z, acc[i][6]);
                acc[i][7] = fmaf(a[i], b1v.w, acc[i][7]);
            }
        }
        __syncthreads();
    }

    #pragma unroll
    for (int i = 0; i < 8; ++i) {
        int gr = m0 + tm * 8 + i;
        if (gr < n_nodes) {
            float4 w0 = make_float4(acc[i][0], acc[i][1], acc[i][2], acc[i][3]);
            float4 w1 = make_float4(acc[i][4], acc[i][5], acc[i][6], acc[i][7]);
            *(float4*)(P + (size_t)gr * 256 + tn * 4)       = w0;
            *(float4*)(P + (size_t)gr * 256 + 128 + tn * 4) = w1;
        }
    }
}

// ---------------------------------------------------------------------------
// Kernel 2: per edge, 16 lanes/edge, all fp32 (known-pass, 221 us).
// ---------------------------------------------------------------------------
__global__ __launch_bounds__(256) void edge_kernel(
    const int* __restrict__ ei, const int* __restrict__ et,
    const float* __restrict__ u, const float* __restrict__ P,
    const float* __restrict__ PetB, const float* __restrict__ W2,
    const float* __restrict__ b2, float* __restrict__ out, int E)
{
    int gtid = blockIdx.x * 256 + threadIdx.x;
    int e = gtid >> 4;
    int l = gtid & 15;
    if (e >= E) return;

    int src = ei[e];
    int dst = ei[E + e];
    int t   = et[e];
    float uu = u[e];

    const float4* ps = (const float4*)(P + (size_t)src * 256);
    const float4* pd = (const float4*)(P + (size_t)dst * 256 + 128);
    const float4* pe = (const float4*)(PetB + (size_t)t * 128);
    const float4* w2 = (const float4*)W2;

    float partial = 0.f;
    #pragma unroll
    for (int j = 0; j < 2; ++j) {
        int idx = l * 2 + j;
        float4 a = ps[idx];
        float4 b = pd[idx];
        float4 c = pe[idx];
        float4 w = w2[idx];
        float h0 = fmaxf(a.x + b.x + c.x, 0.f);
        float h1 = fmaxf(a.y + b.y + c.y, 0.f);
        float h2 = fmaxf(a.z + b.z + c.z, 0.f);
        float h3 = fmaxf(a.w + b.w + c.w, 0.f);
        partial = fmaf(h0, w.x, partial);
        partial = fmaf(h1, w.y, partial);
        partial = fmaf(h2, w.z, partial);
        partial = fmaf(h3, w.w, partial);
    }
    partial += __shfl_xor(partial, 1);
    partial += __shfl_xor(partial, 2);
    partial += __shfl_xor(partial, 4);
    partial += __shfl_xor(partial, 8);

    if (l == 0) {
        float logit = partial + b2[0];
        float g  = logf(uu + EPS_G) - logf(1.f - uu + EPS_G);
        float z  = logit + g;                       // TEMP = 1.0
        float yv = 1.f / (1.f + expf(-z));
        float yh = yv > 0.5f ? 1.f : 0.f;
        float yst = (yh - yv) + yv;
        out[e]         = logit;
        out[E + e]     = yv;
        out[2 * E + e] = yst;
    }
}

// ---------------------------------------------------------------------------
// Lowest-tier fallback: wave(64)/edge direct MLP, fp32.
// ---------------------------------------------------------------------------
__global__ __launch_bounds__(256) void edge_direct_kernel(
    const float* __restrict__ x, const int* __restrict__ ei,
    const int* __restrict__ et, const float* __restrict__ u,
    const float* __restrict__ ee, const float* __restrict__ W1,
    const float* __restrict__ b1, const float* __restrict__ W2,
    const float* __restrict__ b2, float* __restrict__ out, int E)
{
    int wid  = (blockIdx.x * 256 + threadIdx.x) >> 6;
    int lane = threadIdx.x & 63;
    if (wid >= E) return;
    int src = ei[wid], dst = ei[E + wid], t = et[wid];
    int c0 = lane * 2;
    float acc0 = b1[c0], acc1 = b1[c0 + 1];
    for (int k = 0; k < 128; ++k) {
        float xs = x[(size_t)src * 128 + k];
        acc0 = fmaf(xs, W1[k * 128 + c0], acc0);
        acc1 = fmaf(xs, W1[k * 128 + c0 + 1], acc1);
    }
    for (int k = 0; k < 128; ++k) {
        float xd = x[(size_t)dst * 128 + k];
        acc0 = fmaf(xd, W1[(128 + k) * 128 + c0], acc0);
        acc1 = fmaf(xd, W1[(128 + k) * 128 + c0 + 1], acc1);
    }
    for (int k = 0; k < 16; ++k) {
        float ev = ee[t * 16 + k];
        acc0 = fmaf(ev, W1[(256 + k) * 128 + c0], acc0);
        acc1 = fmaf(ev, W1[(256 + k) * 128 + c0 + 1], acc1);
    }
    float partial = fmaxf(acc0, 0.f) * W2[c0] + fmaxf(acc1, 0.f) * W2[c0 + 1];
    #pragma unroll
    for (int off = 1; off < 64; off <<= 1) partial += __shfl_xor(partial, off);
    if (lane == 0) {
        float logit = partial + b2[0];
        float uu = u[wid];
        float g  = logf(uu + EPS_G) - logf(1.f - uu + EPS_G);
        float z  = logit + g;
        float yv = 1.f / (1.f + expf(-z));
        float yh = yv > 0.5f ? 1.f : 0.f;
        float yst = (yh - yv) + yv;
        out[wid]         = logit;
        out[E + wid]     = yv;
        out[2 * E + wid] = yst;
    }
}

// ---------------------------------------------------------------------------
extern "C" void kernel_launch(void* const* d_in, const int* in_sizes, int n_in,
                              void* d_out, int out_size, void* d_ws, size_t ws_size,
                              hipStream_t stream)
{
    const float* x   = (const float*)d_in[0];
    const int*   ei  = (const int*)d_in[1];
    const int*   et  = (const int*)d_in[2];
    const float* u   = (const float*)d_in[3];
    const float* ee  = (const float*)d_in[4];
    const float* W1  = (const float*)d_in[5];
    const float* b1  = (const float*)d_in[6];
    const float* W2  = (const float*)d_in[7];
    const float* b2  = (const float*)d_in[8];
    float* out = (float*)d_out;

    const int n_nodes  = in_sizes[0] / HIDDEN;   // 100000
    const int E        = in_sizes[2];             // 1600000
    const int n_etypes = in_sizes[4] / 16;        // 512

    const size_t needP   = (size_t)n_nodes * 256 * sizeof(float);    // 102.4 MB
    const size_t needPet = (size_t)n_etypes * 128 * sizeof(float);   // 256 KB
    const int    LDS_BIG = 128 * 256 * 4;                            // 131072 B

    if (ws_size >= needP + needPet) {
        float* P    = (float*)d_ws;
        float* PetB = (float*)((char*)d_ws + needP);

        hipLaunchKernelGGL(etype_proj_kernel,
                           dim3((n_etypes * 128 + 255) / 256), dim3(256), 0, stream,
                           ee, W1, b1, PetB, n_etypes);

        // opt into 131 KB dynamic LDS (host-side attribute; graph-capture safe)
        hipError_t rc = hipFuncSetAttribute(
            (const void*)node_proj_big_kernel,
            hipFuncAttributeMaxDynamicSharedMemorySize, LDS_BIG);

        if (rc == hipSuccess) {
            hipLaunchKernelGGL(node_proj_big_kernel,
                               dim3((n_nodes + 127) / 128), dim3(1024), LDS_BIG,
                               stream, x, W1, P, n_nodes);
        } else {
            hipLaunchKernelGGL(node_proj_kernel,
                               dim3((n_nodes + 63) / 64), dim3(256), 0, stream,
                               x, W1, P, n_nodes);
        }

        hipLaunchKernelGGL(edge_kernel,
                           dim3((int)(((size_t)E * 16 + 255) / 256)), dim3(256), 0, stream,
                           ei, et, u, P, PetB, W2, b2, out, E);
    } else {
        hipLaunchKernelGGL(edge_direct_kernel,
                           dim3((E + 3) / 4), dim3(256), 0, stream,
                           x, ei, et, u, ee, W1, b1, W2, b2, out, E);
    }
}